// Round 4
// baseline (43.650 us; speedup 1.0000x reference)
//
#include <hip/hip_runtime.h>
#include <hip/hip_bf16.h>
#include <stdint.h>

// Conv2d, B=32, Cin=64, Cout=128, 3x3, stride 1, pad 1, H=W=56, fp32 in/out.
// Reference's mismatched flatten == standard conv with permuted weights:
// Weff for patch elem (c,di,dj) = K[f/192][(f%192)/64][f%64], f = c*9+di*3+dj.
// Reduction enumeration g = di*192 + dj*64 + c  =>  for fixed di, A's K-slice
// is contiguous in padded-NHWC layout: byte (w*64+c)*2 within row (i+di).
// r4: fully fused — x transposed NCHW->NHWC-bf16 in-LDS per block (no xpT in
// HBM, no big prep kernel). Only a tiny weight-permute kernel remains.

#define B_   32
#define CIN  64
#define COUT 128
#define H_   56
#define HP   58          // spatially padded
#define F_   576         // 9*64 reduction length

typedef __attribute__((ext_vector_type(8))) short bf16x8;
typedef __attribute__((ext_vector_type(4))) float f32x4;

#define WG_ELEMS (COUT*F_)               // 73,728
#define WS_NEEDED ((size_t)WG_ELEMS * 2) // 147 KB
#define NWBLK (WG_ELEMS/256)             // 288 weight blocks

// LDS map (bytes): A bf16 tile [0, 45568); B/scratch buf0 at 45568, buf1 at
// 61952. Total 78336 -> 2 blocks/CU. Scratch rows (f32, slot-swizzled) live
// in the B buffers before B staging starts.
#define A_ALLOC 45568
#define LDS_TOT (A_ALLOC + 2*16384)

// ---------- prepass: K[kh][kw][cin][cout] f32 -> WgT[co][g] bf16 ----------
__global__ __launch_bounds__(256) void prep_w(const float* __restrict__ K,
                                              __hip_bfloat16* __restrict__ WgT) {
  int n = blockIdx.x*256 + threadIdx.x;   // 288 full blocks
  int co = n / F_, g = n % F_;
  int di = g / 192, dj = (g % 192) / 64, c = g & 63;
  int f  = c*9 + di*3 + dj;
  int kh = f / 192, kw = (f % 192) / 64, cc = f & 63;
  WgT[n] = __float2bfloat16(K[(((size_t)kh*3 + kw)*CIN + cc)*COUT + co]);
}

// ---------- fused conv: block = (b, 4 output rows), M=256(224 real), N=128 --
__global__ __launch_bounds__(256, 2) void conv_fused(
    const float* __restrict__ x,
    const __hip_bfloat16* __restrict__ WgT,
    float* __restrict__ out) {
  __shared__ __align__(16) char lds[LDS_TOT];
  const int t    = threadIdx.x;
  const int wave = t >> 6;               // wave w -> output row i0+w
  const int l    = t & 63;
  const int lr   = l & 15, lq = l >> 4;

  // bijective XCD swizzle: 448 = 8 * 56 (neighbor i-tiles share x rows in L2)
  const int bid = blockIdx.x;
  const int swz = (bid & 7) * 56 + (bid >> 3);
  const int bb  = swz / 14;
  const int i0  = (swz % 14) * 4;

  f32x4 acc[4][8];
#pragma unroll
  for (int mi = 0; mi < 4; ++mi)
#pragma unroll
    for (int ni = 0; ni < 8; ++ni) acc[mi][ni] = (f32x4)0.f;

  const float* xb    = x + (size_t)bb*CIN*H_*H_;
  const char*  wbase = (const char*)WgT;
  char* s0 = lds + A_ALLOC;              // scratch row 0 (= B buf0 region)
  char* s1 = s0 + 16384;                 // scratch row 1 (= B buf1 region)

  // scratch layout: [c][16 slots][4 f32], slot = w4 ^ (c & 15)  (256 B per c)
  // -> conflict-free for phaseA writes (c step 1) AND phaseB reads (c step 8).
  auto phaseA = [&](int r, char* s) {    // load x row (i0+r-1) -> f32 scratch
    const int h = i0 + r;                // padded row index
    if (h == 0 || h == HP-1) return;     // pad row: phaseB emits zeros
    const float* xr = xb + (size_t)(h-1)*H_;
    for (int idx = t; idx < CIN*14; idx += 256) {     // 896 f32x4, coalesced
      int c = idx / 14, w4 = idx % 14;
      f32x4 v = *(const f32x4*)(xr + (size_t)c*(H_*H_) + w4*4);
      *(f32x4*)(s + c*256 + (w4 ^ (c & 15))*16) = v;
    }
  };
  auto phaseB = [&](int r, const char* s) {  // scratch -> bf16 A-tile row r
    const int h = i0 + r;
    const bool zrow = (h == 0 || h == HP-1);
    for (int idx = t; idx < HP*8; idx += 256) {       // 464 bf16x8 stores
      int wp = idx >> 3, cg = (idx & 7) * 8;          // wp = padded w' 0..57
      float v[8];
      if (zrow || wp == 0 || wp == HP-1) {
#pragma unroll
        for (int k2 = 0; k2 < 8; ++k2) v[k2] = 0.f;
      } else {
        int w = wp - 1, sl = w >> 2, off = w & 3;
#pragma unroll
        for (int k2 = 0; k2 < 8; ++k2) {
          int c = cg + k2;
          v[k2] = *(const float*)(s + c*256 + ((sl ^ (c & 15))*16) + off*4);
        }
      }
      __align__(16) __hip_bfloat16 tmp[8];
#pragma unroll
      for (int k2 = 0; k2 < 8; ++k2) tmp[k2] = __float2bfloat16(v[k2]);
      int R   = r*HP + wp;                            // A-tile 128B row
      int tot = R*128 + cg*2;
      int adr = (tot & ~127) | ((tot & 127) ^ ((R & 7) << 4));
      *(bf16x8*)(lds + adr) = *(const bf16x8*)tmp;
    }
  };
  auto stageB = [&](int q, int buf) {    // 16 KB: WgT[co][q*64 .. +63]
    const char* wg = wbase + q*128;
    char* Bb = lds + A_ALLOC + buf*16384;
#pragma unroll
    for (int s = 0; s < 4; ++s) {
      int o  = s*4096 + t*16;
      int co = o >> 7;
      const char* src = wg + (size_t)co*1152 + ((o & 127) ^ ((co & 7) << 4));
      __builtin_amdgcn_global_load_lds(
          (const __attribute__((address_space(1))) void*)src,
          (__attribute__((address_space(3))) void*)(Bb + s*4096 + wave*1024),
          16, 0, 0);
    }
  };

  // ---- in-LDS transpose of the block's 6 padded rows (double-buffered) ----
  phaseA(0, s0);                 __syncthreads();
  phaseB(0, s0);  phaseA(1, s1); __syncthreads();
  phaseB(1, s1);  phaseA(2, s0); __syncthreads();
  phaseB(2, s0);  phaseA(3, s1); __syncthreads();
  phaseB(3, s1);  phaseA(4, s0); __syncthreads();
  phaseB(4, s0);  phaseA(5, s1); __syncthreads();
  phaseB(5, s1);  stageB(0, 0);  __syncthreads();   // s0 free -> stage B q=0

  // ---- main loop: 9 K-chunks of 64, B double-buffered ----
#pragma unroll
  for (int q = 0; q < 9; ++q) {
    const int buf = q & 1;
    if (q < 8) stageB(q + 1, buf ^ 1);
    const char* Bb = lds + A_ALLOC + buf*16384;
#pragma unroll
    for (int ks = 0; ks < 2; ++ks) {
      const int kg  = q*64 + ks*32;      // global k (compile-time)
      const int di  = kg / 192;
      const int rem = kg - di*192;       // dj*64 + c-block within di-slab
      bf16x8 a[4], bfr[8];
#pragma unroll
      for (int mi = 0; mi < 4; ++mi) {
        int r   = (wave + di)*HP + mi*16 + lr;
        int tot = r*128 + rem*2 + lq*16;
        int adr = (tot & ~127) | ((tot & 127) ^ (((tot >> 7) & 7) << 4));
        a[mi] = *(const bf16x8*)(lds + adr);
      }
      const int cb = ks*64 + lq*16;
#pragma unroll
      for (int ni = 0; ni < 8; ++ni) {
        int co = ni*16 + lr;
        bfr[ni] = *(const bf16x8*)(Bb + (((co << 7) | cb) ^ ((co & 7) << 4)));
      }
#pragma unroll
      for (int mi = 0; mi < 4; ++mi)
#pragma unroll
        for (int ni = 0; ni < 8; ++ni)
          acc[mi][ni] = __builtin_amdgcn_mfma_f32_16x16x32_bf16(
              a[mi], bfr[ni], acc[mi][ni], 0, 0, 0);
    }
    __syncthreads();
  }

  // epilogue: C/D layout col=lane&15 -> co, row=(lane>>4)*4+reg -> j
  const int i = i0 + wave;
#pragma unroll
  for (int mi = 0; mi < 4; ++mi) {
    int j0 = mi*16 + lq*4;
    if (j0 < H_) {
#pragma unroll
      for (int ni = 0; ni < 8; ++ni) {
        int co = ni*16 + lr;
        float* dst = out + (((size_t)(bb*COUT + co))*H_ + i)*H_ + j0;
        *(f32x4*)dst = acc[mi][ni];
      }
    }
  }
}

// ---------- fallback (workspace too small): naive fp32 direct ----------
__global__ __launch_bounds__(256) void conv_naive(const float* __restrict__ x,
                                                  const float* __restrict__ K,
                                                  float* __restrict__ out) {
  int idx = blockIdx.x*256 + threadIdx.x;
  const int total = B_*COUT*H_*H_;
  if (idx >= total) return;
  int j = idx % H_, i = (idx / H_) % H_, co = (idx / (H_*H_)) % COUT, b = idx / (H_*H_*COUT);
  float s = 0.f;
  for (int c = 0; c < CIN; ++c)
    for (int di = 0; di < 3; ++di) {
      int ii = i + di - 1;
      if (ii < 0 || ii >= H_) continue;
      for (int dj = 0; dj < 3; ++dj) {
        int jj = j + dj - 1;
        if (jj < 0 || jj >= H_) continue;
        int f = c*9 + di*3 + dj;
        int kh = f / 192, kw = (f % 192) / 64, cc = f & 63;
        s += x[(((size_t)b*CIN + c)*H_ + ii)*H_ + jj] *
             K[(((size_t)kh*3 + kw)*CIN + cc)*COUT + co];
      }
    }
  out[idx] = s;
}

extern "C" void kernel_launch(void* const* d_in, const int* in_sizes, int n_in,
                              void* d_out, int out_size, void* d_ws, size_t ws_size,
                              hipStream_t stream) {
  const float* x = (const float*)d_in[0];
  const float* K = (const float*)d_in[1];
  float* out = (float*)d_out;
  if (ws_size >= WS_NEEDED) {
    __hip_bfloat16* WgT = (__hip_bfloat16*)d_ws;
    prep_w<<<NWBLK, 256, 0, stream>>>(K, WgT);
    conv_fused<<<B_*14, 256, 0, stream>>>(x, WgT, out);
  } else {
    conv_naive<<<(B_*COUT*H_*H_ + 255)/256, 256, 0, stream>>>(x, K, out);
  }
}

// Round 5
// 39.411 us; speedup vs baseline: 1.1076x; 1.1076x over previous
//
#include <hip/hip_runtime.h>
#include <hip/hip_bf16.h>
#include <stdint.h>

// Conv2d, B=32, Cin=64, Cout=128, 3x3, stride 1, pad 1, H=W=56, fp32 in/out.
// Reference's mismatched flatten == standard conv with permuted weights:
// Weff for patch elem (c,di,dj) = K[f/192][(f%192)/64][f%64], f = c*9+di*3+dj.
// Reduction order g = di*192 + dj*64 + c => for fixed di, A's K-slice is
// CONTIGUOUS in padded-NHWC layout: byte (w*64+c)*2 within row (i+di).
// r5: two-kernel again (r4 fusion regressed). Conv LDS cut to 61,952 B
// (<64KB) to force 2-block/CU co-residency; B staged in 8KB half-chunks
// (k=32), 18 dbuf iterations; setprio around MFMA; prep transpose scratch
// slot-swizzled (old version had 8-way read conflicts).

#define B_   32
#define CIN  64
#define COUT 128
#define H_   56
#define HP   58          // spatially padded
#define F_   576         // 9*64 reduction length

typedef __attribute__((ext_vector_type(8))) short bf16x8;
typedef __attribute__((ext_vector_type(4))) float f32x4;

#define XP_ELEMS (B_*HP*HP*CIN)          // 6,889,472
#define XP_SLACK 4096
#define XP_TOTAL (XP_ELEMS + XP_SLACK)
#define WG_ELEMS (COUT*F_)               // 73,728
#define WS_NEEDED ((size_t)(XP_TOTAL + WG_ELEMS) * 2)

#define NROW   (B_*HP)                   // 1856 x-row blocks
#define NWBLK  (WG_ELEMS/256)            // 288 weight blocks

// conv LDS (bytes): A tile [0, 45568); B half-chunk bufs at 45568 + buf*8192.
#define A_ALLOC 45568
#define LDS_TOT (A_ALLOC + 2*8192)       // 61,952 < 64KB -> 2 blocks/CU even
                                         // under a 128KB effective pool

// ---------- fused prepass: x NCHW f32 -> padded NHWC bf16; K -> WgT[co][g] ----
__global__ __launch_bounds__(256) void prep_all(const float* __restrict__ x,
                                                const float* __restrict__ K,
                                                __hip_bfloat16* __restrict__ xpT,
                                                __hip_bfloat16* __restrict__ WgT) {
  const int id = blockIdx.x;
  const int t  = threadIdx.x;

  if (id > NROW) {                       // ---- weight permute blocks ----
    int n = (id - (NROW + 1))*256 + t;   // 288 full blocks
    int co = n / F_, g = n % F_;
    int di = g / 192, dj = (g % 192) / 64, c = g & 63;
    int f  = c*9 + di*3 + dj;
    int kh = f / 192, kw = (f % 192) / 64, cc = f & 63;
    WgT[n] = __float2bfloat16(K[(((size_t)kh*3 + kw)*CIN + cc)*COUT + co]);
    return;
  }
  if (id == NROW) {                      // ---- slack zero-fill ----
    bf16x8 z = (bf16x8)0;
    for (int idx = t; idx < XP_SLACK/8; idx += 256)
      ((bf16x8*)(xpT + XP_ELEMS))[idx] = z;
    return;
  }

  const int b = id / HP, h = id % HP;
  __hip_bfloat16* orow = xpT + (size_t)(b*HP + h) * HP * CIN;
  if (h == 0 || h == HP-1) {             // top/bottom pad rows
    bf16x8 z = (bf16x8)0;
    for (int idx = t; idx < HP*CIN/8; idx += 256) ((bf16x8*)orow)[idx] = z;
    return;
  }
  // slot-swizzled scratch: scr[c][slot][4], slot = (w4 + (c>>3)) & 15.
  // Conflict-free-by-construction for f32x4 writes (fixed c, w4 varies) AND
  // transpose scalar reads (fixed (sl,off), c = 8*g+k2 -> slot spans g).
  __shared__ __align__(16) float scr[CIN*64];      // 16 KB
  const float* xrow = x + ((size_t)(b*CIN)*H_ + (h-1)) * H_;
  for (int idx = t; idx < CIN*14; idx += 256) {    // coalesced f32x4 reads
    int c = idx / 14, w4 = idx % 14;
    f32x4 v = *(const f32x4*)(xrow + (size_t)c*(H_*H_) + w4*4);
    *(f32x4*)&scr[c*64 + ((w4 + (c >> 3)) & 15)*4] = v;
  }
  __syncthreads();
  for (int idx = t; idx < HP*8; idx += 256) {      // bf16x8 writes
    int wp = idx >> 3, cg = (idx & 7) * 8;
    __align__(16) __hip_bfloat16 tmp[8];
    if (wp == 0 || wp == HP-1) {
#pragma unroll
      for (int k2 = 0; k2 < 8; ++k2) tmp[k2] = __float2bfloat16(0.f);
    } else {
      int w = wp - 1, sl = w >> 2, off = w & 3;
#pragma unroll
      for (int k2 = 0; k2 < 8; ++k2) {
        int c = cg + k2;
        tmp[k2] = __float2bfloat16(scr[c*64 + ((sl + (c >> 3)) & 15)*4 + off]);
      }
    }
    *(bf16x8*)(orow + (size_t)wp*CIN + cg) = *(const bf16x8*)tmp;
  }
}

// ---------- main: implicit GEMM, block = (b, 4 rows), M=256(224 real), N=128
// A staged ONCE (6 contiguous padded rows, XOR-swizzled src / swizzled reads);
// B double-buffered in 8KB half-chunks (k=32), 18 iterations, natural 64B
// rows (bank-balanced, no swizzle needed).
__global__ __launch_bounds__(256, 2) void conv_mfma(
    const __hip_bfloat16* __restrict__ xpT,
    const __hip_bfloat16* __restrict__ WgT,
    float* __restrict__ out) {
  __shared__ __align__(16) char lds[LDS_TOT];
  const int t    = threadIdx.x;
  const int wave = t >> 6;               // wave w -> output row i0+w
  const int l    = t & 63;
  const int lr   = l & 15, lq = l >> 4;

  // bijective XCD swizzle: 448 = 8 * 56
  const int bid = blockIdx.x;
  const int swz = (bid & 7) * 56 + (bid >> 3);
  const int bb  = swz / 14;
  const int i0  = (swz % 14) * 4;

  f32x4 acc[4][8];
#pragma unroll
  for (int mi = 0; mi < 4; ++mi)
#pragma unroll
    for (int ni = 0; ni < 8; ++ni) acc[mi][ni] = (f32x4)0.f;

  const char* xb    = (const char*)xpT + (size_t)(bb*HP + i0) * HP * CIN * 2;
  const char* wbase = (const char*)WgT;

  // ---- stage A once: 45,056 B contiguous, swizzled source, linear dest ----
#pragma unroll
  for (int s = 0; s < 11; ++s) {
    int o = s*4096 + t*16;
    int m = o >> 7;
    const char* src = xb + ((o & ~127) | ((o & 127) ^ ((m & 7) << 4)));
    __builtin_amdgcn_global_load_lds(
        (const __attribute__((address_space(1))) void*)src,
        (__attribute__((address_space(3))) void*)(lds + s*4096 + wave*1024),
        16, 0, 0);
  }

  auto stageBh = [&](int hc, int buf) {  // 8 KB: WgT[co][hc*32 .. +32]
    const char* wg = wbase + hc*64;      // k byte offset
    char* Bb = lds + A_ALLOC + buf*8192;
#pragma unroll
    for (int s = 0; s < 2; ++s) {
      int o  = s*4096 + t*16;
      int co = o >> 6;                   // 64B per co row
      const char* src = wg + (size_t)co*1152 + (o & 63);
      __builtin_amdgcn_global_load_lds(
          (const __attribute__((address_space(1))) void*)src,
          (__attribute__((address_space(3))) void*)(Bb + s*4096 + wave*1024),
          16, 0, 0);
    }
  };

  stageBh(0, 0);
  __syncthreads();

  // ---- main loop: 18 half-chunks of k=32, B double-buffered ----
#pragma unroll
  for (int hc = 0; hc < 18; ++hc) {
    const int buf = hc & 1;
    if (hc < 17) stageBh(hc + 1, buf ^ 1);
    const char* Bb = lds + A_ALLOC + buf*8192;
    const int kg  = hc*32;
    const int di  = kg / 192;
    const int rem = kg - di*192;         // dj*64 + c0 within di-slab
    bf16x8 a[4], bq[8];
#pragma unroll
    for (int mi = 0; mi < 4; ++mi) {
      int r   = (wave + di)*HP + mi*16 + lr;
      int tot = r*128 + rem*2 + lq*16;
      int adr = (tot & ~127) | ((tot & 127) ^ (((tot >> 7) & 7) << 4));
      a[mi] = *(const bf16x8*)(lds + adr);
    }
#pragma unroll
    for (int ni = 0; ni < 8; ++ni) {
      int co = ni*16 + lr;
      bq[ni] = *(const bf16x8*)(Bb + co*64 + lq*16);
    }
    __builtin_amdgcn_s_setprio(1);
#pragma unroll
    for (int mi = 0; mi < 4; ++mi)
#pragma unroll
      for (int ni = 0; ni < 8; ++ni)
        acc[mi][ni] = __builtin_amdgcn_mfma_f32_16x16x32_bf16(
            a[mi], bq[ni], acc[mi][ni], 0, 0, 0);
    __builtin_amdgcn_s_setprio(0);
    __syncthreads();
  }

  // epilogue: C/D layout col=lane&15 -> co, row=(lane>>4)*4+reg -> j
  const int i = i0 + wave;
#pragma unroll
  for (int mi = 0; mi < 4; ++mi) {
    int j0 = mi*16 + lq*4;
    if (j0 < H_) {
#pragma unroll
      for (int ni = 0; ni < 8; ++ni) {
        int co = ni*16 + lr;
        float* dst = out + (((size_t)(bb*COUT + co))*H_ + i)*H_ + j0;
        *(f32x4*)dst = acc[mi][ni];
      }
    }
  }
}

// ---------- fallback (workspace too small): naive fp32 direct ----------
__global__ __launch_bounds__(256) void conv_naive(const float* __restrict__ x,
                                                  const float* __restrict__ K,
                                                  float* __restrict__ out) {
  int idx = blockIdx.x*256 + threadIdx.x;
  const int total = B_*COUT*H_*H_;
  if (idx >= total) return;
  int j = idx % H_, i = (idx / H_) % H_, co = (idx / (H_*H_)) % COUT, b = idx / (H_*H_*COUT);
  float s = 0.f;
  for (int c = 0; c < CIN; ++c)
    for (int di = 0; di < 3; ++di) {
      int ii = i + di - 1;
      if (ii < 0 || ii >= H_) continue;
      for (int dj = 0; dj < 3; ++dj) {
        int jj = j + dj - 1;
        if (jj < 0 || jj >= H_) continue;
        int f = c*9 + di*3 + dj;
        int kh = f / 192, kw = (f % 192) / 64, cc = f & 63;
        s += x[(((size_t)b*CIN + c)*H_ + ii)*H_ + jj] *
             K[(((size_t)kh*3 + kw)*CIN + cc)*COUT + co];
      }
    }
  out[idx] = s;
}

extern "C" void kernel_launch(void* const* d_in, const int* in_sizes, int n_in,
                              void* d_out, int out_size, void* d_ws, size_t ws_size,
                              hipStream_t stream) {
  const float* x = (const float*)d_in[0];
  const float* K = (const float*)d_in[1];
  float* out = (float*)d_out;
  if (ws_size >= WS_NEEDED) {
    __hip_bfloat16* xpT = (__hip_bfloat16*)d_ws;
    __hip_bfloat16* WgT = xpT + XP_TOTAL;
    prep_all<<<NROW + 1 + NWBLK, 256, 0, stream>>>(x, K, xpT, WgT);
    conv_mfma<<<B_*14, 256, 0, stream>>>(xpT, WgT, out);
  } else {
    conv_naive<<<(B_*COUT*H_*H_ + 255)/256, 256, 0, stream>>>(x, K, out);
  }
}